// Round 10
// baseline (467.941 us; speedup 1.0000x reference)
//
#include <hip/hip_runtime.h>
#include <hip/hip_bf16.h>

#define HIDDEN 128
#define DEPTH 4
#define INTER 512
#define NSTATE 16
#define DT_RANK 8
#define EPS_RMS 1e-5f
#define MTOK 512            // B*T
#define KIN 150528

typedef __attribute__((ext_vector_type(8))) short bf16x8;
typedef __attribute__((ext_vector_type(4))) float f32x4;

__device__ __forceinline__ unsigned short f2bf(float f) {
  unsigned int u = __builtin_bit_cast(unsigned int, f);
  u += 0x7fffu + ((u >> 16) & 1u);
  return (unsigned short)(u >> 16);
}
__device__ __forceinline__ float silu_f(float x) {
  return x / (1.0f + __expf(-x));
}

// ---------------------------------------------------------------------------
// zero_part: 4 MB partial buffer zero (1024 x 256 x float4).
// ---------------------------------------------------------------------------
__global__ __launch_bounds__(256) void zero_part(float* __restrict__ p)
{
  const size_t i = (size_t)blockIdx.x * 256 + threadIdx.x;
  ((float4*)p)[i] = (float4){0.f, 0.f, 0.f, 0.f};
}

// ---------------------------------------------------------------------------
// Projection GEMM v3 (R3-proven, ~85 us): zero-duplication tiling.
// ---------------------------------------------------------------------------
__global__ __launch_bounds__(512) void proj_gemm(
    const float* __restrict__ x, const float* __restrict__ w,
    float* __restrict__ partial)
{
  const int bid = blockIdx.x;          // 0..255
  const int mb = (bid >> 3) & 3;       // 0..3  (M-tile of 128 rows)
  const int kb = (bid & 7) + (bid >> 5) * 8;   // 0..63 (XCD-clustered)
  const int nchunk = 18 + (kb < 24 ? 1 : 0);
  const int c0 = kb * 18 + (kb < 24 ? kb : 24);

  __shared__ char sm[256 * 256];       // 256 rows (x:0-127, w:128-255) x 256 B

  const int tid = threadIdx.x;
  const int lane = tid & 63;
  const int wv = tid >> 6;             // 0..7
  const int wm2 = wv >> 2;             // 0..1  M-half (64 rows)
  const int wn4 = wv & 3;              // 0..3  N-quarter (32 cols)
  const int fr = lane & 15;
  const int kq = lane >> 4;            // 0..3
  const int l31 = lane & 31;
  const int rpar = lane >> 5;          // 0/1

  const float* gptr = (wv < 4)
      ? (x + (size_t)(mb * 128 + wv * 32 + rpar) * KIN + l31 * 4)
      : (w + (size_t)((wv - 4) * 32 + rpar) * KIN + l31 * 4);

  f32x4 acc[4][2];
  #pragma unroll
  for (int mi = 0; mi < 4; ++mi) {
    acc[mi][0] = (f32x4){0.f, 0.f, 0.f, 0.f};
    acc[mi][1] = (f32x4){0.f, 0.f, 0.f, 0.f};
  }

  float4 rv[16];
  {
    const float* base = gptr + (size_t)c0 * 128;
    #pragma unroll
    for (int j = 0; j < 16; ++j)
      rv[j] = *(const float4*)(base + (size_t)(j * 2) * KIN);
  }

  for (int cc = 0; cc < nchunk; ++cc) {
    #pragma unroll
    for (int j = 0; j < 16; ++j) {
      const int r = wv * 32 + j * 2 + rpar;
      const int phys = (l31 * 8) ^ ((r & 7) << 4);
      ushort4 bq = {f2bf(rv[j].x), f2bf(rv[j].y), f2bf(rv[j].z), f2bf(rv[j].w)};
      *(ushort4*)(sm + r * 256 + phys) = bq;
    }
    __syncthreads();
    if (cc + 1 < nchunk) {
      const float* base = gptr + (size_t)(c0 + cc + 1) * 128;
      #pragma unroll
      for (int j = 0; j < 16; ++j)
        rv[j] = *(const float4*)(base + (size_t)(j * 2) * KIN);
    }
    #pragma unroll
    for (int ks = 0; ks < 4; ++ks) {
      const int log = ks * 64 + kq * 16;
      bf16x8 a[4];
      #pragma unroll
      for (int mi = 0; mi < 4; ++mi) {
        const int row = wm2 * 64 + mi * 16 + fr;
        a[mi] = *(const bf16x8*)(sm + row * 256 + (log ^ ((row & 7) << 4)));
      }
      #pragma unroll
      for (int ni = 0; ni < 2; ++ni) {
        const int row = 128 + wn4 * 32 + ni * 16 + fr;
        const bf16x8 b = *(const bf16x8*)(sm + row * 256 + (log ^ ((row & 7) << 4)));
        #pragma unroll
        for (int mi = 0; mi < 4; ++mi)
          acc[mi][ni] = __builtin_amdgcn_mfma_f32_16x16x32_bf16(a[mi], b, acc[mi][ni], 0, 0, 0);
      }
    }
    __syncthreads();
  }
  float* hp = partial + (size_t)(kb & 15) * (MTOK * HIDDEN);
  #pragma unroll
  for (int mi = 0; mi < 4; ++mi)
    #pragma unroll
    for (int ni = 0; ni < 2; ++ni)
      #pragma unroll
      for (int r = 0; r < 4; ++r) {
        const int row = mb * 128 + wm2 * 64 + mi * 16 + kq * 4 + r;
        const int col = wn4 * 32 + ni * 16 + fr;
        atomicAdd(hp + (size_t)row * HIDDEN + col, acc[mi][ni][r]);
      }
}

// ---------------------------------------------------------------------------
// fusedA v2: OUTPUT-SPLIT across 2 blocks per token-pair (grid 512, 2/CU).
// bh = bid>>8. Both halves: stage y2, full out_proj (dup, cheap), full rms.
// in_proj splits by output range e = bh*512 + e_local -> each ipw row read
// by exactly ONE block per token pair (no weight duplication, unlike R7's
// token split). h written by bh0 only. mode 2 launches grid 256 (bh==0).
// ---------------------------------------------------------------------------
__global__ __launch_bounds__(512, 4) void fusedA(
    int mode,
    const float* __restrict__ part, const float* __restrict__ pb,
    const float* __restrict__ yT, const float* __restrict__ gate_g,
    float* __restrict__ h_g,
    const float* __restrict__ opw,   // pre-offset (layer l)
    const float* __restrict__ nw,    // pre-offset norm row (or nwf)
    const float* __restrict__ ipw,   // pre-offset (layer l+1)
    float* __restrict__ hs_g, float* __restrict__ gate_out,
    float* __restrict__ dout)
{
  const int bh = blockIdx.x >> 8;  // output half (0/1)
  const int m0 = (blockIdx.x & 255) * 2;
  const int tid = threadIdx.x;     // 0..511
  const int o2 = tid >> 1;         // 0..255
  const int half = tid & 1;
  const int t = o2 >> 7, d = o2 & 127;
  __shared__ float y2[2][512];
  __shared__ float hrow[2][128];
  __shared__ float hn[2][128];

  float hv;
  if (mode == 0) {
    hv = pb[d];
    #pragma unroll
    for (int s = 0; s < 16; ++s)
      hv += part[(size_t)s * (MTOK * HIDDEN) + (size_t)(m0 + t) * 128 + d];
  } else {
    #pragma unroll
    for (int j = 0; j < 2; ++j) {
      const int o = tid + j * 512;
      const int tt = o >> 9, i = o & 511;
      const int gt = m0 + tt;
      const int b = gt >> 8, tb = gt & 255;
      const float yv = yT[((size_t)b * 512 + i) * 256 + tb];
      const float g  = gate_g[(size_t)gt * 512 + i];
      y2[tt][i] = yv * silu_f(g);
    }
    __syncthreads();
    // out_proj: 2 threads per (t,d), k split 256+256 (duplicated in both bh)
    const float4* yp = (const float4*)(&y2[t][0] + half * 256);
    const float4* wp = (const float4*)(opw + (size_t)d * 512 + half * 256);
    float a0 = 0.f, a1 = 0.f, a2 = 0.f, a3 = 0.f;
    #pragma unroll 8
    for (int kk = 0; kk < 64; ++kk) {
      const float4 yv = yp[kk], wv4 = wp[kk];
      a0 += yv.x * wv4.x; a1 += yv.y * wv4.y;
      a2 += yv.z * wv4.z; a3 += yv.w * wv4.w;
    }
    float a = (a0 + a1) + (a2 + a3);
    a += __shfl_xor(a, 1);          // both halves hold full dot
    hv = h_g[(size_t)(m0 + t) * 128 + d] + a;
  }
  if (mode != 2 && bh == 0 && half == 0) h_g[(size_t)(m0 + t) * 128 + d] = hv;
  if (half == 0) hrow[t][d] = hv;
  __syncthreads();
  // rmsnorm (waves 0..3 replicate tokens 0/1; waves 0,1 write)
  {
    const int wvi = tid >> 6, ln = tid & 63;
    const int tt = wvi & 1;
    const float v0 = hrow[tt][ln], v1 = hrow[tt][ln + 64];
    float ss = v0 * v0 + v1 * v1;
    #pragma unroll
    for (int off = 1; off < 64; off <<= 1) ss += __shfl_xor(ss, off);
    const float rr = rsqrtf(ss * (1.0f / 128.0f) + EPS_RMS);
    if (mode == 2) {
      if (wvi < 2) {
        dout[(size_t)(m0 + tt) * 128 + ln]      = v0 * rr * nw[ln];
        dout[(size_t)(m0 + tt) * 128 + ln + 64] = v1 * rr * nw[ln + 64];
      }
      return;
    }
    if (wvi < 2) {
      hn[tt][ln]      = v0 * rr * nw[ln];
      hn[tt][ln + 64] = v1 * rr * nw[ln + 64];
    }
  }
  __syncthreads();
  // in_proj: this half owns outputs e = bh*512 + [0,512): 1024 work items
  #pragma unroll
  for (int j = 0; j < 2; ++j) {
    const int o = tid + j * 512;
    const int tt = o >> 9, el = o & 511;
    const int e = bh * 512 + el;
    const float4* hp4 = (const float4*)&hn[tt][0];
    const float4* wp4 = (const float4*)(ipw + (size_t)e * 128);
    float a0 = 0.f, a1 = 0.f, a2 = 0.f, a3 = 0.f;
    #pragma unroll
    for (int kk = 0; kk < 32; ++kk) {
      const float4 hvv = hp4[kk], wv4 = wp4[kk];
      a0 += hvv.x * wv4.x; a1 += hvv.y * wv4.y;
      a2 += hvv.z * wv4.z; a3 += hvv.w * wv4.w;
    }
    const float a = (a0 + a1) + (a2 + a3);
    if (bh == 0) hs_g[(size_t)(m0 + tt) * 512 + e] = a;
    else         gate_out[(size_t)(m0 + tt) * 512 + (e - 512)] = a;
  }
}

// ---------------------------------------------------------------------------
// convxp v2: OUTPUT-SPLIT (grid 512, 2 blocks/CU). Both halves stage hs5 and
// compute full conv + x_proj (cheap dup); writes split: uG channels by half,
// dt by channel range, B/C by bh0.
// ---------------------------------------------------------------------------
__global__ __launch_bounds__(512, 4) void convxp(
    const float* __restrict__ hs_g, const float* __restrict__ cw,
    const float* __restrict__ cb, const float* __restrict__ xpw,
    const float* __restrict__ dtw, const float* __restrict__ dtb,
    float* __restrict__ uG, float* __restrict__ dtG,
    float* __restrict__ Bm, float* __restrict__ Cm)
{
  const int bh = blockIdx.x >> 8;
  const int m0 = (blockIdx.x & 255) * 2;
  const int b = m0 >> 8, tb0 = m0 & 255;
  const int tid = threadIdx.x;
  __shared__ float hs5[5][512];
  __shared__ float u4[2][512];
  __shared__ float si[2][40];
  for (int o = tid; o < 2560; o += 512) {        // hs rows tb0-3 .. tb0+1
    const int j = o >> 9, i = o & 511;
    const int ct = tb0 - 3 + j;
    hs5[j][i] = (ct >= 0) ? hs_g[((size_t)b * 256 + ct) * 512 + i] : 0.f;
  }
  __syncthreads();
  #pragma unroll
  for (int j = 0; j < 2; ++j) {                  // conv + silu -> u (full)
    const int o = tid + j * 512;
    const int t = o >> 9, i = o & 511;
    const float4 c4v = *(const float4*)(cw + (size_t)i * 4);
    const float s = cb[i] + c4v.x * hs5[t][i] + c4v.y * hs5[t + 1][i]
                          + c4v.z * hs5[t + 2][i] + c4v.w * hs5[t + 3][i];
    const float uu = silu_f(s);
    u4[t][i] = uu;
    if ((i >> 8) == bh)                          // write own channel half
      uG[((size_t)b * 256 + tb0 + t) * 512 + i] = uu;
  }
  __syncthreads();
  if (tid < 160) {                               // x_proj (full, dup)
    const int pid = tid >> 1, half = tid & 1;
    const int t = pid / 40, e = pid % 40;
    const float4* up = (const float4*)(&u4[t][0] + half * 256);
    const float4* wp = (const float4*)(xpw + (size_t)e * 512 + half * 256);
    float a0 = 0.f, a1 = 0.f, a2 = 0.f, a3 = 0.f;
    #pragma unroll 8
    for (int kk = 0; kk < 64; ++kk) {
      const float4 uv = up[kk], wv4 = wp[kk];
      a0 += uv.x * wv4.x; a1 += uv.y * wv4.y;
      a2 += uv.z * wv4.z; a3 += uv.w * wv4.w;
    }
    float a = (a0 + a1) + (a2 + a3);
    a += __shfl_xor(a, 1);
    if (half == 0) si[t][e] = a;
  }
  __syncthreads();
  if (bh == 0 && tid < 64) {                     // B, C rows (bh0)
    const int t = tid >> 5, q = tid & 31;
    if (q < 16) Bm[(size_t)(m0 + t) * 16 + q] = si[t][8 + q];
    else        Cm[(size_t)(m0 + t) * 16 + (q - 16)] = si[t][24 + (q - 16)];
  }
  {                                              // dt: own channel half
    const int o = bh * 512 + tid;                // 0..1023 over both halves
    const int t = o >> 9, i = o & 511;
    float a0 = dtb[i];
    const float* dr = dtw + (size_t)i * 8;
    #pragma unroll
    for (int r = 0; r < 8; ++r) a0 += si[t][r] * dr[r];
    const float sp = (a0 > 20.f) ? a0 : log1pf(__expf(a0));
    dtG[((size_t)b * 256 + tb0 + t) * 512 + i] = sp;
  }
}

// ---------------------------------------------------------------------------
// scan_k (unchanged, 4 blocks/CU): chunked SSM scan. grid 1024, block 256.
// ---------------------------------------------------------------------------
__global__ __launch_bounds__(256) void scan_k(
    const float* __restrict__ uG, const float* __restrict__ dtG,
    const float* __restrict__ Bm, const float* __restrict__ Cm,
    const float* __restrict__ Alog, const float* __restrict__ Dssm,
    float* __restrict__ yT)
{
  const int blk = blockIdx.x;       // 0..1023
  const int b = blk >> 9, i = blk & 511;
  const int tid = threadIdx.x;
  __shared__ float dt_r[256], u_r[256];
  __shared__ float B_l[256][17], C_l[256][17];
  __shared__ float e_l[16][17], P_l[16][17];
  dt_r[tid] = dtG[((size_t)b * 256 + tid) * 512 + i];
  u_r[tid]  = uG [((size_t)b * 256 + tid) * 512 + i];
  #pragma unroll
  for (int j = 0; j < 16; ++j) {
    const int o = tid + j * 256;
    B_l[o >> 4][o & 15] = Bm[(size_t)b * 4096 + o];
    C_l[o >> 4][o & 15] = Cm[(size_t)b * 4096 + o];
  }
  __syncthreads();
  const int c = tid >> 4, n = tid & 15;
  const float Av = -__expf(Alog[(size_t)i * 16 + n]);
  const float Dv = Dssm[i];
  float aj[16], xj[16];
  float s = 0.f, P = 1.f;
  #pragma unroll
  for (int j = 0; j < 16; ++j) {    // pass 1: local scan from 0
    const int t = c * 16 + j;
    const float dtv = dt_r[t];
    const float a = __expf(Av * dtv);
    const float xx = dtv * B_l[t][n] * u_r[t];
    aj[j] = a; xj[j] = xx;
    s = a * s + xx; P *= a;
  }
  e_l[c][n] = s; P_l[c][n] = P;
  __syncthreads();
  float s0 = 0.f;                   // stitch chunk prefixes
  for (int cc = 0; cc < c; ++cc)
    s0 = P_l[cc][n] * s0 + e_l[cc][n];
  s = s0;
  #pragma unroll
  for (int j = 0; j < 16; ++j) {    // pass 2: replay with true state
    const int t = c * 16 + j;
    s = aj[j] * s + xj[j];
    float p = s * C_l[t][n];
    p += __shfl_xor(p, 1); p += __shfl_xor(p, 2);
    p += __shfl_xor(p, 4); p += __shfl_xor(p, 8);
    if (n == 0)
      yT[((size_t)b * 512 + i) * 256 + t] = p + u_r[t] * Dv;  // coalesced
  }
}

extern "C" void kernel_launch(void* const* d_in, const int* in_sizes, int n_in,
                              void* d_out, int out_size, void* d_ws, size_t ws_size,
                              hipStream_t stream)
{
  (void)in_sizes; (void)n_in; (void)out_size; (void)ws_size;
  const float* x    = (const float*)d_in[0];
  const float* pw   = (const float*)d_in[1];
  const float* pb   = (const float*)d_in[2];
  const float* ipw  = (const float*)d_in[3];
  const float* cw   = (const float*)d_in[4];
  const float* cb   = (const float*)d_in[5];
  const float* xpw  = (const float*)d_in[6];
  const float* dtw  = (const float*)d_in[7];
  const float* dtb  = (const float*)d_in[8];
  const float* Alog = (const float*)d_in[9];
  const float* Dssm = (const float*)d_in[10];
  const float* opw  = (const float*)d_in[11];
  const float* nw   = (const float*)d_in[12];
  const float* nwf  = (const float*)d_in[13];
  float* out = (float*)d_out;

  float* ws   = (float*)d_ws;                 // ~10 MB scratch
  float* part = ws;                           // 16 * 65536 (atomic-accumulated)
  float* h    = part + 16 * 65536;            // 65536
  float* hs   = h + 65536;                    // 262144
  float* gate = hs + 262144;                  // 262144
  float* uG   = gate + 262144;                // 262144 (token-major)
  float* dtG  = uG + 262144;                  // 262144 (token-major)
  float* Bm   = dtG + 262144;                 // 8192
  float* Cm   = Bm + 8192;                    // 8192
  float* yT   = Cm + 8192;                    // 262144 (channel-major)

  zero_part<<<dim3(1024), 256, 0, stream>>>(part);
  proj_gemm<<<dim3(256), 512, 0, stream>>>(x, pw, part);

  // first: h from part + rms + in_proj(l=0)  (output-split, grid 512)
  fusedA<<<dim3(512), 512, 0, stream>>>(0, part, pb, nullptr, nullptr, h,
                                        nullptr, nw, ipw, hs, gate, nullptr);
  for (int l = 0; l < DEPTH; ++l) {
    convxp<<<dim3(512), 512, 0, stream>>>(
        hs, cw + (size_t)l * 2048, cb + (size_t)l * 512,
        xpw + (size_t)l * 40 * 512, dtw + (size_t)l * 512 * 8,
        dtb + (size_t)l * 512, uG, dtG, Bm, Cm);
    scan_k<<<dim3(1024), 256, 0, stream>>>(
        uG, dtG, Bm, Cm, Alog + (size_t)l * 512 * 16, Dssm + (size_t)l * 512, yT);
    if (l < DEPTH - 1)
      fusedA<<<dim3(512), 512, 0, stream>>>(1, nullptr, nullptr, yT, gate, h,
          opw + (size_t)l * 128 * 512, nw + (size_t)(l + 1) * 128,
          ipw + (size_t)(l + 1) * 1024 * 128, hs, gate, nullptr);
    else
      fusedA<<<dim3(256), 512, 0, stream>>>(2, nullptr, nullptr, yT, gate, h,
          opw + (size_t)l * 128 * 512, nwf, nullptr, nullptr, nullptr, out);
  }
}